// Round 3
// baseline (1042.335 us; speedup 1.0000x reference)
//
#include <hip/hip_runtime.h>
#include <hip/hip_bf16.h>
#include <math.h>

// Problem constants (B=4, S=4096, D=2048, E=8, K=2, R=16, SCALING=1.0)
// Inputs fp32 (reference dtype); OUTPUT BUFFER fp32 (reference output dtype).
// The harness compares against a bf16-rounded np reference (8-ulp bf16 floor).
#define NTOK   16384   // B*S
#define DIM    2048
#define NEXP   8
#define RANK   16
#define TOPK   2

// Wave-level dot of a 2048-long fp32 row against x held in 32 regs/lane.
// Lane l owns elements [4*(i*64+l) .. +3] for i in 0..7 (16-byte coalesced loads).
__device__ __forceinline__ float wave_dot(const float* xr,
                                          const float* __restrict__ w,
                                          int lane) {
  float acc = 0.f;
  const float4* p = (const float4*)w;
  #pragma unroll
  for (int i = 0; i < 8; ++i) {
    float4 v = p[i * 64 + lane];
    acc = fmaf(xr[i * 4 + 0], v.x, acc);
    acc = fmaf(xr[i * 4 + 1], v.y, acc);
    acc = fmaf(xr[i * 4 + 2], v.z, acc);
    acc = fmaf(xr[i * 4 + 3], v.w, acc);
  }
  #pragma unroll
  for (int off = 32; off > 0; off >>= 1) acc += __shfl_down(acc, off);
  return acc;  // valid in lane 0
}

__global__ __launch_bounds__(256) void mole_fused_kernel(
    const float* __restrict__ x,       // [NTOK][DIM] fp32
    const float* __restrict__ gate_W,  // [NEXP][DIM] fp32
    const float* __restrict__ gate_b,  // [NEXP] fp32
    const float* __restrict__ A,       // [NEXP][RANK][DIM] fp32
    const float* __restrict__ Bm,      // [NEXP][DIM][RANK] fp32
    float* __restrict__ out,           // [NTOK][DIM] fp32
    float* __restrict__ probs_out) {   // [NTOK][NEXP] fp32
  const int token = blockIdx.x;
  const int t     = threadIdx.x;
  const int lane  = t & 63;
  const int wave  = t >> 6;

  __shared__ float logits[NEXP];
  __shared__ float gh[TOPK * RANK];  // gelu(h) for the two selected experts
  __shared__ int   sel[TOPK];

  // ---- Load x row into 32 regs per lane (each wave holds the full row) ----
  const float* xrow = x + (size_t)token * DIM;
  float xr[32];
  {
    const float4* xp = (const float4*)xrow;
    #pragma unroll
    for (int i = 0; i < 8; ++i) {
      float4 v = xp[i * 64 + lane];
      xr[i * 4 + 0] = v.x;
      xr[i * 4 + 1] = v.y;
      xr[i * 4 + 2] = v.z;
      xr[i * 4 + 3] = v.w;
    }
  }

  // ---- Gate logits: wave w computes experts w and w+4 ----
  {
    float l0 = wave_dot(xr, gate_W + (size_t)wave * DIM, lane);
    float l1 = wave_dot(xr, gate_W + (size_t)(wave + 4) * DIM, lane);
    if (lane == 0) {
      logits[wave]     = l0 + gate_b[wave];
      logits[wave + 4] = l1 + gate_b[wave + 4];
    }
  }
  __syncthreads();

  // ---- Softmax + top-2 (thread 0; jax top_k tie-break = lowest index) ----
  if (t == 0) {
    float m = logits[0];
    #pragma unroll
    for (int e = 1; e < NEXP; ++e) m = fmaxf(m, logits[e]);
    float ex[NEXP], s = 0.f;
    #pragma unroll
    for (int e = 0; e < NEXP; ++e) { ex[e] = __expf(logits[e] - m); s += ex[e]; }
    float inv = 1.f / s;
    #pragma unroll
    for (int e = 0; e < NEXP; ++e)
      probs_out[(size_t)token * NEXP + e] = ex[e] * inv;
    int i0 = 0;
    #pragma unroll
    for (int e = 1; e < NEXP; ++e) if (logits[e] > logits[i0]) i0 = e;
    int i1 = (i0 == 0) ? 1 : 0;
    #pragma unroll
    for (int e = 0; e < NEXP; ++e)
      if (e != i0 && logits[e] > logits[i1]) i1 = e;
    sel[0] = i0; sel[1] = i1;
  }
  __syncthreads();

  // ---- h = gelu(x . A[e][r]) for the 2 selected experts (32 wave-dots) ----
  {
    int e = sel[wave >> 1];          // waves 0,1 -> sel[0]; waves 2,3 -> sel[1]
    int rbase = (wave & 1) * 8;
    for (int jj = 0; jj < 8; ++jj) {
      int r = rbase + jj;
      float h = wave_dot(xr, A + ((size_t)e * RANK + r) * DIM, lane);
      if (lane == 0) {
        // exact gelu: h * 0.5 * (1 + erf(h / sqrt(2)))
        gh[(wave >> 1) * RANK + r] = 0.5f * h * (1.f + erff(h * 0.70710678118654752f));
      }
    }
  }
  __syncthreads();

  // ---- Combine: out[d] = sum_{k,r} gh[k*16+r] * Bm[sel[k]][d][r] ----
  float ghr[TOPK * RANK];
  #pragma unroll
  for (int j = 0; j < TOPK * RANK; ++j) ghr[j] = gh[j];  // LDS broadcast
  int s0 = sel[0], s1 = sel[1];

  const int d0 = t * 8;  // 256 threads * 8 = 2048
  float acc[8];
  #pragma unroll
  for (int dd = 0; dd < 8; ++dd) acc[dd] = 0.f;

  #pragma unroll
  for (int k = 0; k < TOPK; ++k) {
    int e = (k == 0) ? s0 : s1;
    const float4* q = (const float4*)(Bm + ((size_t)e * DIM + d0) * RANK);
    #pragma unroll
    for (int dd = 0; dd < 8; ++dd) {
      float4 v0 = q[dd * 4 + 0];   // Bm[e][d0+dd][0..3]
      float4 v1 = q[dd * 4 + 1];   // Bm[e][d0+dd][4..7]
      float4 v2 = q[dd * 4 + 2];   // Bm[e][d0+dd][8..11]
      float4 v3 = q[dd * 4 + 3];   // Bm[e][d0+dd][12..15]
      float a = acc[dd];
      const float* gk = ghr + k * RANK;
      a = fmaf(gk[0],  v0.x, a); a = fmaf(gk[1],  v0.y, a);
      a = fmaf(gk[2],  v0.z, a); a = fmaf(gk[3],  v0.w, a);
      a = fmaf(gk[4],  v1.x, a); a = fmaf(gk[5],  v1.y, a);
      a = fmaf(gk[6],  v1.z, a); a = fmaf(gk[7],  v1.w, a);
      a = fmaf(gk[8],  v2.x, a); a = fmaf(gk[9],  v2.y, a);
      a = fmaf(gk[10], v2.z, a); a = fmaf(gk[11], v2.w, a);
      a = fmaf(gk[12], v3.x, a); a = fmaf(gk[13], v3.y, a);
      a = fmaf(gk[14], v3.z, a); a = fmaf(gk[15], v3.w, a);
      acc[dd] = a;
    }
  }

  // ---- Store 8 fp32 as two 16B writes (SCALING == 1.0) ----
  float* op = out + (size_t)token * DIM + d0;
  *(float4*)(op + 0) = make_float4(acc[0], acc[1], acc[2], acc[3]);
  *(float4*)(op + 4) = make_float4(acc[4], acc[5], acc[6], acc[7]);
}

extern "C" void kernel_launch(void* const* d_in, const int* in_sizes, int n_in,
                              void* d_out, int out_size, void* d_ws, size_t ws_size,
                              hipStream_t stream) {
  const float* x      = (const float*)d_in[0];
  const float* gate_W = (const float*)d_in[1];
  const float* gate_b = (const float*)d_in[2];
  const float* A      = (const float*)d_in[3];
  const float* Bm     = (const float*)d_in[4];

  float* out   = (float*)d_out;                  // [NTOK][DIM]
  float* probs = out + (size_t)NTOK * DIM;       // [NTOK][NEXP]

  mole_fused_kernel<<<dim3(NTOK), dim3(256), 0, stream>>>(
      x, gate_W, gate_b, A, Bm, out, probs);
}

// Round 4
// 309.932 us; speedup vs baseline: 3.3631x; 3.3631x over previous
//
#include <hip/hip_runtime.h>
#include <math.h>

// B=4,S=4096 -> NTOK=16384; D=2048; E=8; R=16; K=2; SCALING=1
// Inputs fp32; d_out fp32: out[16384][2048] then probs[16384][8].
// ws layout (bf16/ushort): W1[144][2048] | Wg_lo[16][2048] | Bm2[2048][128] | Hm[16384][128]
#define NTOK 16384
#define DIM  2048
#define NEXP 8
#define RANK 16

typedef unsigned short ushort_t;
typedef unsigned int   uint_t;
typedef __attribute__((ext_vector_type(8))) short bf16x8;
typedef __attribute__((ext_vector_type(4))) float f32x4;

__device__ __forceinline__ ushort_t f2bf(float f) {
  union { float f; uint_t u; } v; v.f = f;
  uint_t r = (v.u + 0x7FFFu + ((v.u >> 16) & 1u)) >> 16;
  return (ushort_t)r;
}
__device__ __forceinline__ float bf2f(ushort_t s) {
  union { uint_t u; float f; } v; v.u = ((uint_t)s) << 16;
  return v.f;
}

// ---------------- K0: weight prep (fp32 -> bf16, transposes) ----------------
__global__ __launch_bounds__(256) void k0_prep(
    const float* __restrict__ gW, const float* __restrict__ A,
    const float* __restrict__ Bm,
    ushort_t* __restrict__ W1, ushort_t* __restrict__ Wgl,
    ushort_t* __restrict__ Bm2) {
  int b = blockIdx.x, t = threadIdx.x;
  if (b < 1152) {                       // W1[144][2048]
    int idx = b * 256 + t;
    int row = idx >> 11, col = idx & 2047;
    float v = (row < 8) ? gW[row * 2048 + col]
            : (row < 16) ? 0.f
            : A[(size_t)(row - 16) * 2048 + col];
    W1[idx] = f2bf(v);
  } else if (b < 1280) {                // Wg_lo[16][2048]
    int idx = (b - 1152) * 256 + t;
    int row = idx >> 11, col = idx & 2047;
    float v = (row < 8) ? gW[row * 2048 + col] : 0.f;
    ushort_t hi = f2bf(v);
    Wgl[idx] = f2bf(v - bf2f(hi));
  } else {                              // Bm2[2048][128]: Bm2[d][e*16+r]=Bm[e][d][r]
    int idx = (b - 1280) * 256 + t;     // 0..262143
    int d = idx >> 7, c = idx & 127, e = c >> 4, r = c & 15;
    Bm2[idx] = f2bf(Bm[((size_t)e * 2048 + d) * 16 + r]);
  }
}

// ---------------- K1: gate + h  (C[32 x 144] = x . W1^T) ----------------
#define BK  64
#define BKP 72   // pad to break ds_read_b128 row-stride conflicts (2-way only)

__global__ __launch_bounds__(256) void k1_gate_h(
    const float* __restrict__ x, const float* __restrict__ gate_b,
    const ushort_t* __restrict__ W1, const ushort_t* __restrict__ Wgl,
    ushort_t* __restrict__ Hm, float* __restrict__ probs) {
  __shared__ __align__(16) ushort_t xs_hi[32][BKP];
  __shared__ __align__(16) ushort_t xs_lo[32][BKP];
  __shared__ __align__(16) ushort_t wh[144][BKP];
  __shared__ __align__(16) ushort_t wl[16][BKP];
  __shared__ float Cs[32][152];
  __shared__ int sel0s[32], sel1s[32];

  const int t = threadIdx.x;
  const int lane = t & 63, wave = t >> 6;
  const int l15 = lane & 15, q = lane >> 4;
  const int mt = wave & 1;        // M-tile (16 tokens)
  const int ng = wave >> 1;       // 0: N-tiles 0-3 (incl gate corr), 1: N-tiles 4-8
  const int ntiles = ng ? 5 : 4;
  const int tok0 = blockIdx.x * 32;

  f32x4 acc[5];
  #pragma unroll
  for (int i = 0; i < 5; ++i) acc[i] = (f32x4)0.f;

  const float4* xg = (const float4*)(x + (size_t)tok0 * DIM);
  const uint2* wg1 = (const uint2*)W1;
  const uint2* wgl = (const uint2*)Wgl;

  for (int ch = 0; ch < 32; ++ch) {
    const int k0 = ch * BK;
    // ---- stage x (fp32 -> bf16 hi/lo) ----
    #pragma unroll
    for (int i = 0; i < 2; ++i) {
      int idx = t + i * 256;            // 0..511
      int row = idx >> 4, c4 = idx & 15;
      float4 v = xg[row * (DIM / 4) + (k0 >> 2) + c4];
      float vv[4] = {v.x, v.y, v.z, v.w};
      ushort_t h4[4], l4[4];
      #pragma unroll
      for (int j = 0; j < 4; ++j) {
        h4[j] = f2bf(vv[j]);
        l4[j] = f2bf(vv[j] - bf2f(h4[j]));
      }
      *(uint2*)&xs_hi[row][c4 * 4] = *(const uint2*)h4;
      *(uint2*)&xs_lo[row][c4 * 4] = *(const uint2*)l4;
    }
    // ---- stage W1 chunk (144 x 64 bf16) ----
    #pragma unroll
    for (int i = 0; i < 9; ++i) {
      int idx = t + i * 256;            // 0..2303
      int row = idx >> 4, c = idx & 15;
      uint2 v = wg1[row * (DIM / 4) + (k0 >> 2) + c];
      *(uint2*)&wh[row][c * 4] = v;
    }
    // ---- stage Wg_lo chunk (16 x 64) ----
    {
      int row = t >> 4, c = t & 15;
      uint2 v = wgl[row * (DIM / 4) + (k0 >> 2) + c];
      *(uint2*)&wl[row][c * 4] = v;
    }
    __syncthreads();

    // ---- MFMA ----
    #pragma unroll
    for (int kk = 0; kk < BK; kk += 32) {
      bf16x8 ah = *(const bf16x8*)&xs_hi[mt * 16 + l15][kk + q * 8];
      if (ng == 0) {
        bf16x8 al  = *(const bf16x8*)&xs_lo[mt * 16 + l15][kk + q * 8];
        bf16x8 bgl = *(const bf16x8*)&wl[l15][kk + q * 8];
        bf16x8 b0  = *(const bf16x8*)&wh[l15][kk + q * 8];
        acc[0] = __builtin_amdgcn_mfma_f32_16x16x32_bf16(ah, b0, acc[0], 0, 0, 0);
        acc[0] = __builtin_amdgcn_mfma_f32_16x16x32_bf16(al, b0, acc[0], 0, 0, 0);
        acc[0] = __builtin_amdgcn_mfma_f32_16x16x32_bf16(ah, bgl, acc[0], 0, 0, 0);
        #pragma unroll
        for (int nt = 1; nt < 4; ++nt) {
          bf16x8 b = *(const bf16x8*)&wh[nt * 16 + l15][kk + q * 8];
          acc[nt] = __builtin_amdgcn_mfma_f32_16x16x32_bf16(ah, b, acc[nt], 0, 0, 0);
        }
      } else {
        #pragma unroll
        for (int nt = 0; nt < 5; ++nt) {
          bf16x8 b = *(const bf16x8*)&wh[64 + nt * 16 + l15][kk + q * 8];
          acc[nt] = __builtin_amdgcn_mfma_f32_16x16x32_bf16(ah, b, acc[nt], 0, 0, 0);
        }
      }
    }
    __syncthreads();
  }

  // ---- write C tiles to LDS (col = lane&15, row = quad*4+reg) ----
  const int colbase = ng ? 64 : 0;
  #pragma unroll
  for (int i = 0; i < 5; ++i) {
    if (i < ntiles) {
      #pragma unroll
      for (int r = 0; r < 4; ++r)
        Cs[mt * 16 + q * 4 + r][colbase + i * 16 + l15] = acc[i][r];
    }
  }
  __syncthreads();

  // ---- softmax + top-2 per token ----
  if (t < 32) {
    int m = t;
    float lg[NEXP];
    #pragma unroll
    for (int e = 0; e < NEXP; ++e) lg[e] = Cs[m][e] + gate_b[e];
    float mx = lg[0];
    #pragma unroll
    for (int e = 1; e < NEXP; ++e) mx = fmaxf(mx, lg[e]);
    float ex[NEXP], s = 0.f;
    #pragma unroll
    for (int e = 0; e < NEXP; ++e) { ex[e] = __expf(lg[e] - mx); s += ex[e]; }
    float inv = 1.f / s;
    float4 p0 = make_float4(ex[0] * inv, ex[1] * inv, ex[2] * inv, ex[3] * inv);
    float4 p1 = make_float4(ex[4] * inv, ex[5] * inv, ex[6] * inv, ex[7] * inv);
    float* pp = probs + (size_t)(tok0 + m) * NEXP;
    *(float4*)pp = p0; *(float4*)(pp + 4) = p1;
    int i0 = 0;
    #pragma unroll
    for (int e = 1; e < NEXP; ++e) if (lg[e] > lg[i0]) i0 = e;
    int i1 = (i0 == 0) ? 1 : 0;
    #pragma unroll
    for (int e = 0; e < NEXP; ++e) if (e != i0 && lg[e] > lg[i1]) i1 = e;
    sel0s[m] = i0; sel1s[m] = i1;
  }
  __syncthreads();

  // ---- gelu + mask -> Hm bf16 ----
  {
    int m = t >> 3, e = t & 7;
    int on = (e == sel0s[m]) | (e == sel1s[m]);
    ushort_t ov[16];
    #pragma unroll
    for (int r = 0; r < RANK; ++r) {
      float v = Cs[m][16 + e * 16 + r];
      float g = on ? (0.5f * v * (1.f + erff(v * 0.70710678118654752f))) : 0.f;
      ov[r] = f2bf(g);
    }
    ushort_t* hp = Hm + ((size_t)(tok0 + m) * 128 + e * 16);
    *(uint4*)hp       = *(const uint4*)&ov[0];
    *(uint4*)(hp + 8) = *(const uint4*)&ov[8];
  }
}

// ---------------- K2: out[16384][2048] = Hm[.,128] . Bm2[128,.] ----------------
// Block = 1 wave (64 thr), 64 tokens (4 M-tiles) x 256 cols (16 N-tiles). LDS-free.
__global__ __launch_bounds__(64) void k2_combine(
    const ushort_t* __restrict__ Hm, const ushort_t* __restrict__ Bm2,
    float* __restrict__ out) {
  const int lane = threadIdx.x;
  const int l15 = lane & 15, q = lane >> 4;
  const int t0 = blockIdx.x * 64;
  const int nb = blockIdx.y * 256;

  // A-frags: 4 M-tiles x 4 k-steps, held in registers for the whole block
  bf16x8 a[4][4];
  #pragma unroll
  for (int mt = 0; mt < 4; ++mt)
    #pragma unroll
    for (int kk = 0; kk < 4; ++kk)
      a[mt][kk] = *(const bf16x8*)&Hm[(size_t)(t0 + mt * 16 + l15) * 128 + kk * 32 + q * 8];

  for (int i = 0; i < 16; ++i) {
    int n0 = nb + i * 16;
    bf16x8 b0 = *(const bf16x8*)&Bm2[(size_t)(n0 + l15) * 128 + 0 * 32 + q * 8];
    bf16x8 b1 = *(const bf16x8*)&Bm2[(size_t)(n0 + l15) * 128 + 1 * 32 + q * 8];
    bf16x8 b2 = *(const bf16x8*)&Bm2[(size_t)(n0 + l15) * 128 + 2 * 32 + q * 8];
    bf16x8 b3 = *(const bf16x8*)&Bm2[(size_t)(n0 + l15) * 128 + 3 * 32 + q * 8];
    #pragma unroll
    for (int mt = 0; mt < 4; ++mt) {
      f32x4 c = (f32x4)0.f;
      c = __builtin_amdgcn_mfma_f32_16x16x32_bf16(a[mt][0], b0, c, 0, 0, 0);
      c = __builtin_amdgcn_mfma_f32_16x16x32_bf16(a[mt][1], b1, c, 0, 0, 0);
      c = __builtin_amdgcn_mfma_f32_16x16x32_bf16(a[mt][2], b2, c, 0, 0, 0);
      c = __builtin_amdgcn_mfma_f32_16x16x32_bf16(a[mt][3], b3, c, 0, 0, 0);
      #pragma unroll
      for (int r = 0; r < 4; ++r)
        out[(size_t)(t0 + mt * 16 + q * 4 + r) * DIM + n0 + l15] = c[r];
    }
  }
}

extern "C" void kernel_launch(void* const* d_in, const int* in_sizes, int n_in,
                              void* d_out, int out_size, void* d_ws, size_t ws_size,
                              hipStream_t stream) {
  const float* x      = (const float*)d_in[0];
  const float* gate_W = (const float*)d_in[1];
  const float* gate_b = (const float*)d_in[2];
  const float* A      = (const float*)d_in[3];
  const float* Bm     = (const float*)d_in[4];

  float* out   = (float*)d_out;                 // [NTOK][DIM]
  float* probs = out + (size_t)NTOK * DIM;      // [NTOK][NEXP]

  ushort_t* W1  = (ushort_t*)d_ws;              // [144][2048]
  ushort_t* Wgl = W1 + 144 * 2048;              // [16][2048]
  ushort_t* Bm2 = Wgl + 16 * 2048;              // [2048][128]
  ushort_t* Hm  = Bm2 + 2048 * 128;             // [16384][128]

  k0_prep<<<dim3(2304), dim3(256), 0, stream>>>(gate_W, A, Bm, W1, Wgl, Bm2);
  k1_gate_h<<<dim3(NTOK / 32), dim3(256), 0, stream>>>(x, gate_b, W1, Wgl, Hm, probs);
  k2_combine<<<dim3(NTOK / 64, DIM / 256), dim3(64), 0, stream>>>(Hm, Bm2, out);
}